// Round 3
// baseline (658.476 us; speedup 1.0000x reference)
//
#include <hip/hip_runtime.h>
#include <hip/hip_cooperative_groups.h>
#include <math.h>

namespace cg = cooperative_groups;

#define NTOT 65536
#define LCH 128
#define WRM 128
#define CCH 512          // NTOT / LCH
#define NBLK 256         // sort/stagex grid

__device__ __forceinline__ float d_softplus(float x){
  return fmaxf(x, 0.f) + log1pf(__expf(-fabsf(x)));
}
__device__ __forceinline__ float d_sigmoid(float x){
  return 1.f / (1.f + __expf(-x));
}
__device__ __forceinline__ float fast_rcp(float x){
  return __builtin_amdgcn_rcpf(x);
}
template<int CTRL>
__device__ __forceinline__ float dpp_mov(float x){
  return __int_as_float(__builtin_amdgcn_update_dpp(0, __float_as_int(x), CTRL, 0xF, 0xF, true));
}
// DPP ctrls: 0xB1 quad_perm xor1, 0x4E quad_perm xor2, 0x121 row_ror:1,
// 0x140 row_mirror, 0x141 row_half_mirror.

__device__ __forceinline__ unsigned block_incl_scan(unsigned v, unsigned* buf, int t){
  buf[t] = v; __syncthreads();
  #pragma unroll
  for (int off = 1; off < 256; off <<= 1){
    unsigned u = (t >= off) ? buf[t-off] : 0u;
    __syncthreads();
    buf[t] += u;
    __syncthreads();
  }
  unsigned r = buf[t];
  __syncthreads();
  return r;
}

// ============ cooperative: 4-pass stable radix sort + unsort + stage X ============
__global__ __launch_bounds__(256) void k_sortstage(
    const float* __restrict__ g, const float* __restrict__ sh,
    unsigned* __restrict__ keys0, unsigned* __restrict__ keys1,
    unsigned* __restrict__ idx0, unsigned* __restrict__ idx1,
    unsigned* __restrict__ ghist, unsigned* __restrict__ dtot,
    unsigned* __restrict__ unsrt,
    const float* __restrict__ inprojW, const float* __restrict__ inprojb,
    const float* __restrict__ m_inW, const float* __restrict__ m_dtW,
    const float* __restrict__ m_dtb, const float* __restrict__ m_BW,
    const float* __restrict__ m_CW,
    float* __restrict__ STEP)
{
  cg::grid_group gg = cg::this_grid();
  __shared__ unsigned sh_a[256], sh_b[256], sh_w[1024];
  __shared__ float w_in[512], w_dt[512], w_B[512], w_C[512], w_dtb[32], w_ip[16], w_ipb[8];
  int t = threadIdx.x, blk = blockIdx.x;
  int gid = blk*256 + t;
  int lane = t & 63, wv = t >> 6;

  #pragma unroll
  for (int p = 0; p < 4; ++p){
    unsigned key, id;
    if (p == 0){ key = __float_as_uint(g[gid]) & 0x7fffffffu; id = (unsigned)gid; }
    else {
      const unsigned* ks = (p & 1) ? keys0 : keys1;
      const unsigned* is_ = (p & 1) ? idx0  : idx1;
      key = ks[gid]; id = is_[gid];
    }
    unsigned* kd = (p == 0) ? keys0 : ((p & 1) ? keys1 : keys0);
    unsigned* id_ = (p == 0) ? idx0 : ((p & 1) ? idx1 : idx0);
    unsigned dig = (key >> (p*8)) & 255u;
    // hist (own 256 keys)
    sh_a[t] = 0u; __syncthreads();
    atomicAdd(&sh_a[dig], 1u); __syncthreads();
    ghist[t*NBLK + blk] = sh_a[t];
    gg.sync();
    // per-digit scan over blocks: block b owns digit b
    unsigned v = ghist[blk*NBLK + t];
    unsigned incl = block_incl_scan(v, sh_b, t);
    ghist[blk*NBLK + t] = incl - v;
    if (t == 255) dtot[blk] = incl;
    gg.sync();
    // digit base + per-block run offsets
    unsigned dv = dtot[t];
    unsigned incl2 = block_incl_scan(dv, sh_b, t);
    sh_a[t] = (incl2 - dv) + ghist[t*NBLK + blk];
    sh_w[t] = 0u; sh_w[256+t] = 0u; sh_w[512+t] = 0u; sh_w[768+t] = 0u;
    __syncthreads();
    // stable rank: intra-wave ballot + cross-wave counts
    unsigned long long m = ~0ull;
    #pragma unroll
    for (int b = 0; b < 8; ++b){
      unsigned long long bb = __ballot((dig >> b) & 1u);
      m &= ((dig >> b) & 1u) ? bb : ~bb;
    }
    unsigned rank = (unsigned)__popcll(m & ((1ull << lane) - 1ull));
    unsigned cnt  = (unsigned)__popcll(m);
    if (rank == 0) sh_w[wv*256 + dig] = cnt;
    __syncthreads();
    unsigned pos = sh_a[dig] + rank;
    for (int w2 = 0; w2 < wv; ++w2) pos += sh_w[w2*256 + dig];
    kd[pos] = key; id_[pos] = id;
    gg.sync();
  }
  // sorted order now in idx1 (passes: ->0 ->1 ->0 ->1)
  unsigned sj = idx1[gid];       // original index of sorted position gid
  unsrt[sj] = (unsigned)gid;

  // ---- stage X (per sorted position gid) ----
  for (int k = t; k < 512; k += 256){ w_in[k]=m_inW[k]; w_dt[k]=m_dtW[k]; w_B[k]=m_BW[k]; w_C[k]=m_CW[k]; }
  if (t < 32) w_dtb[t] = m_dtb[t];
  if (t < 16) w_ip[t]  = inprojW[t];
  if (t < 8)  w_ipb[t] = inprojb[t];
  __syncthreads();
  float gj = g[sj], sjv = sh[sj];
  float x[8];
  #pragma unroll
  for (int mm = 0; mm < 8; ++mm) x[mm] = w_ip[mm*2]*gj + w_ip[mm*2+1]*sjv + w_ipb[mm];
  int pair = gid >> 1, sub = gid & 1;
  for (int dir = 0; dir < 2; ++dir){
    const float* inW = &w_in[dir*256];
    float xb[16], z[16];
    #pragma unroll
    for (int k = 0; k < 16; ++k){
      float a = 0.f, b = 0.f;
      #pragma unroll
      for (int mm = 0; mm < 8; ++mm){ a += inW[k*8+mm]*x[mm]; b += inW[(16+k)*8+mm]*x[mm]; }
      xb[k] = a; z[k] = b;
    }
    const float* dtW = &w_dt[dir*256];
    const float* BW  = &w_B[dir*256];
    const float* CW  = &w_C[dir*256];
    float* basep = STEP + (size_t)(dir*(NTOT/2) + pair)*192;
    #pragma unroll
    for (int k = 0; k < 16; ++k){
      float u = w_dtb[dir*16+k];
      #pragma unroll
      for (int mm = 0; mm < 16; ++mm) u += dtW[k*16+mm]*xb[mm];
      float dt = d_softplus(u);
      float zz = z[k];
      float sz = zz * d_sigmoid(zz);
      *(float4*)(basep + k*8 + sub*4) = make_float4(dt, dt*xb[k], sz, xb[k]);
      float bb = 0.f, cc = 0.f;
      #pragma unroll
      for (int mm = 0; mm < 16; ++mm){ bb += BW[k*16+mm]*xb[mm]; cc += CW[k*16+mm]*xb[mm]; }
      *(float2*)(basep + 128 + k*4 + sub*2) = make_float2(bb, cc);
    }
  }
}

// ============ fused scan: warm-up-from-zero chunked recurrence ============
// grid (CCH, 2). thread t: d = t>>4 (channel), s = t&15 (state).
__global__ __launch_bounds__(256) void k_scan_fused(
    const float* __restrict__ STEP, const float* __restrict__ Alog,
    const float* __restrict__ rope, const float* __restrict__ m_D,
    const float* __restrict__ mfwd, const float* __restrict__ mbwd,
    float* __restrict__ V, float* __restrict__ dout)
{
  __shared__ float lds[6144];    // 24 KB staging tile: 64 positions x 96 floats
  __shared__ float ldsV[1024];   // 4 KB V tile for coalesced writeout
  int c = blockIdx.x, dir = blockIdx.y;
  int t = threadIdx.x, d = t >> 4, s = t & 15;
  int lane = t & 63;
  int src = (lane & 48) | ((s + 15) & 15);
  float Ah = -__expf(Alog[dir*256 + d*16 + s]) * 0.5f;
  float rp = rope[dir*256 + d*16 + s];
  float Dd = m_D[dir*16 + d];
  bool fwd = (dir == 0);
  (void)src;
  int warm = ((fwd && c == 0) || (!fwd && c == CCH-1)) ? 0 : WRM;
  int T = (LCH + warm) >> 6;
  int warmT = warm >> 6;
  float h = (warm == 0) ? (fwd ? mfwd[t] : mbwd[t]) : 0.f;
  float* Vp = V + (size_t)dir*NTOT*16;
  const float* Sp = STEP + (size_t)dir*(NTOT/2)*192;

  float4 pf[6];
  #define TILELO(j) (fwd ? (c*LCH - warm + (j)*64) : ((c+1)*LCH + warm - ((j)+1)*64))
  {
    const float4* gp = (const float4*)(Sp + (size_t)(TILELO(0) >> 1)*192);
    #pragma unroll
    for (int k = 0; k < 6; ++k) pf[k] = gp[t + k*256];
  }
  for (int j = 0; j < T; ++j){
    if (j) __syncthreads();                       // staging + ldsV reuse barrier
    #pragma unroll
    for (int k = 0; k < 6; ++k) ((float4*)lds)[t + k*256] = pf[k];
    __syncthreads();
    if (j + 1 < T){
      const float4* gp = (const float4*)(Sp + (size_t)(TILELO(j+1) >> 1)*192);
      #pragma unroll
      for (int k = 0; k < 6; ++k) pf[k] = gp[t + k*256];
    }
    bool real = (j >= warmT);
    int lo = TILELO(j);
    for (int mb = 0; mb < 16; ++mb){
      float yv[4];
      #pragma unroll
      for (int q = 0; q < 4; ++q){
        int m = mb*4 + q;
        int lm = fwd ? m : 63 - m;
        int pr = lm >> 1, sub = lm & 1;
        float4 dd = *(const float4*)&lds[pr*192 + d*8 + sub*4];
        float2 sv = *(const float2*)&lds[pr*192 + 128 + s*4 + sub*2];
        float dt = dd.x, dxb = dd.y;
        float xh = dt * Ah;
        float Ab = (1.f + xh) * fast_rcp(1.f - xh + 1e-8f);
        // |ph| = |dt*rope| <= ~0.2 -> 5th-order Taylor exact to fp32
        float ph = dt * rp;
        float p2 = ph * ph;
        float ccos = 1.f - p2*(0.5f - 0.041666668f*p2);
        float ssin = ph*(1.f - 0.16666667f*p2);
        float a = Ab * ccos;
        float b = -Ab * ssin;
        float hm = dpp_mov<0x121>(h);             // roll(h,1): lane s <- s-1
        h = fmaf(a, h, fmaf(b, hm, dxb * sv.x));
        if (real){
          float v = h * sv.y;
          v += dpp_mov<0xB1>(v);
          v += dpp_mov<0x4E>(v);
          v += dpp_mov<0x140>(v);
          v += dpp_mov<0x141>(v);                 // full 16-lane sum
          yv[q] = fmaf(v, dd.z, Dd * dd.w);       // y*silu(z) + D*xb
        }
      }
      if (real && s < 4){
        float val = (s == 0) ? yv[0] : ((s == 1) ? yv[1] : ((s == 2) ? yv[2] : yv[3]));
        int p = fwd ? (mb*4 + s) : (63 - (mb*4 + s));
        ldsV[p*16 + d] = val;
      }
    }
    if (real){
      __syncthreads();
      float4 vv = ((const float4*)ldsV)[t];
      ((float4*)(Vp + (size_t)lo*16))[t] = vv;    // coalesced 4 KB tile store
    }
  }
  #undef TILELO
  if ((fwd && c == CCH-1) || (!fwd && c == 0))
    dout[5*NTOT + dir*256 + t] = h;               // new_fwd / new_bwd
}

// ============ final: outW projection (gather by unsort) + GRU + PEER ============
__global__ __launch_bounds__(256) void k_final(
    const float* __restrict__ g, const float* __restrict__ sh,
    const float* __restrict__ gru_state, const unsigned* __restrict__ unsrt,
    const float* __restrict__ V, const float* __restrict__ m_outW,
    const float* __restrict__ Wz, const float* __restrict__ bz,
    const float* __restrict__ Wr, const float* __restrict__ br,
    const float* __restrict__ Wh, const float* __restrict__ bh,
    const float* __restrict__ qW, const float* __restrict__ kA, const float* __restrict__ kB,
    const float* __restrict__ eW1, const float* __restrict__ eb1,
    const float* __restrict__ eW2, const float* __restrict__ eb2,
    float* __restrict__ dout)
{
  __shared__ float sWz[88], sWr[88], sWh[88], sbz[4], sbr[4], sbh[4];
  __shared__ float sqW[704], skA[192], skB[192], sOW[256];
  __shared__ float sW1[2304], sb1[2304], sW2[2304], sb2[144];
  int t = threadIdx.x;
  for (int k = t; k < 88; k += 256){ sWz[k]=Wz[k]; sWr[k]=Wr[k]; sWh[k]=Wh[k]; }
  if (t < 4){ sbz[t]=bz[t]; sbr[t]=br[t]; sbh[t]=bh[t]; }
  sOW[t] = m_outW[t];
  for (int k = t; k < 704; k += 256) sqW[k]=qW[k];
  for (int k = t; k < 192; k += 256){ skA[k]=kA[k]; skB[k]=kB[k]; }
  for (int k = t; k < 2304; k += 256){ sW1[k]=eW1[k]; sb1[k]=eb1[k]; sW2[k]=eW2[k]; }
  for (int k = t; k < 144; k += 256) sb2[k]=eb2[k];
  __syncthreads();
  int i = blockIdx.x*256 + t;
  float gi = g[i], si = sh[i];
  unsigned j = unsrt[i];
  float xin[22];
  xin[0] = gi; xin[1] = si;
  #pragma unroll
  for (int dir = 0; dir < 2; ++dir){
    const float* vp = V + (size_t)dir*NTOT*16 + (size_t)j*16;
    float v[16];
    #pragma unroll
    for (int k = 0; k < 4; ++k){
      float4 f = ((const float4*)vp)[k];
      v[k*4] = f.x; v[k*4+1] = f.y; v[k*4+2] = f.z; v[k*4+3] = f.w;
    }
    #pragma unroll
    for (int m = 0; m < 8; ++m){
      float a = 0.f;
      #pragma unroll
      for (int k = 0; k < 16; ++k) a += sOW[dir*128 + m*16 + k]*v[k];
      xin[2 + dir*8 + m] = a;
    }
  }
  float h[4];
  #pragma unroll
  for (int k = 0; k < 4; ++k) h[k] = gru_state[i*4 + k];
  float zg[4], r[4];
  #pragma unroll
  for (int o = 0; o < 4; ++o){
    float az = sbz[o], ar = sbr[o];
    #pragma unroll
    for (int c = 0; c < 18; ++c){ az += sWz[o*22+c]*xin[c]; ar += sWr[o*22+c]*xin[c]; }
    #pragma unroll
    for (int c = 0; c < 4; ++c){ az += sWz[o*22+18+c]*h[c]; ar += sWr[o*22+18+c]*h[c]; }
    zg[o] = d_sigmoid(az);
    r[o]  = d_sigmoid(ar);
  }
  float ng[4];
  #pragma unroll
  for (int o = 0; o < 4; ++o){
    float ah = sbh[o];
    #pragma unroll
    for (int c = 0; c < 18; ++c) ah += sWh[o*22+c]*xin[c];
    #pragma unroll
    for (int c = 0; c < 4; ++c) ah += sWh[o*22+18+c]*(r[c]*h[c]);
    float ht = tanhf(ah);
    ng[o] = (1.f - zg[o])*h[o] + zg[o]*ht;
  }
  float pin[22];
  #pragma unroll
  for (int k = 0; k < 4; ++k) pin[k] = ng[k];
  #pragma unroll
  for (int m = 0; m < 16; ++m) pin[4+m] = xin[2+m];
  pin[20] = gi; pin[21] = si;
  float total = 0.f;
  #pragma unroll
  for (int hh = 0; hh < 4; ++hh){
    float qv[8];
    #pragma unroll
    for (int o = 0; o < 8; ++o){
      float a = 0.f;
      #pragma unroll
      for (int c = 0; c < 22; ++c) a += sqW[hh*176 + o*22 + c]*pin[c];
      qv[o] = a;
    }
    int ia = 0; float best = -1e30f;
    #pragma unroll
    for (int k = 0; k < 12; ++k){
      float sc = 0.f;
      #pragma unroll
      for (int m = 0; m < 4; ++m) sc += skA[hh*48 + k*4 + m]*qv[m];
      if (sc > best){ best = sc; ia = k; }
    }
    int ib = 0; best = -1e30f;
    #pragma unroll
    for (int k = 0; k < 12; ++k){
      float sc = 0.f;
      #pragma unroll
      for (int m = 0; m < 4; ++m) sc += skB[hh*48 + k*4 + m]*qv[4+m];
      if (sc > best){ best = sc; ib = k; }
    }
    int e = ia*12 + ib;
    float outv = sb2[e];
    #pragma unroll
    for (int u = 0; u < 16; ++u){
      float z1 = fmaxf(sW1[e*16+u]*gi + sb1[e*16+u], 0.f);
      outv += sW2[e*16+u]*z1;
    }
    total += outv;
  }
  total *= 0.25f;
  dout[i] = gi + 0.1f*total;
  #pragma unroll
  for (int k = 0; k < 4; ++k) dout[NTOT + i*4 + k] = ng[k];
}

extern "C" void kernel_launch(void* const* d_in, const int* in_sizes, int n_in,
                              void* d_out, int out_size, void* d_ws, size_t ws_size,
                              hipStream_t stream)
{
  const float* grad     = (const float*)d_in[0];
  const float* sharp    = (const float*)d_in[1];
  const float* gru_st   = (const float*)d_in[2];
  const float* mfwd     = (const float*)d_in[3];
  const float* mbwd     = (const float*)d_in[4];
  const float* inprojW  = (const float*)d_in[5];
  const float* inprojb  = (const float*)d_in[6];
  const float* m_inW    = (const float*)d_in[7];
  const float* m_dtW    = (const float*)d_in[8];
  const float* m_dtb    = (const float*)d_in[9];
  const float* m_BW     = (const float*)d_in[10];
  const float* m_CW     = (const float*)d_in[11];
  const float* m_Alog   = (const float*)d_in[12];
  const float* m_D      = (const float*)d_in[13];
  const float* m_rope   = (const float*)d_in[14];
  const float* m_outW   = (const float*)d_in[15];
  const float* gWz      = (const float*)d_in[16];
  const float* gbz      = (const float*)d_in[17];
  const float* gWr      = (const float*)d_in[18];
  const float* gbr      = (const float*)d_in[19];
  const float* gWh      = (const float*)d_in[20];
  const float* gbh      = (const float*)d_in[21];
  const float* peer_qW  = (const float*)d_in[22];
  const float* keysA    = (const float*)d_in[23];
  const float* keysB    = (const float*)d_in[24];
  const float* eW1      = (const float*)d_in[25];
  const float* eb1      = (const float*)d_in[26];
  const float* eW2      = (const float*)d_in[27];
  const float* eb2      = (const float*)d_in[28];
  float* out = (float*)d_out;

  char* base = (char*)d_ws;
  size_t off = 0;
  auto alloc = [&](size_t bytes)->void*{
    void* p = (void*)(base + off);
    off = (off + bytes + 255) & ~(size_t)255;
    return p;
  };
  unsigned* keys0 = (unsigned*)alloc((size_t)NTOT*4);
  unsigned* keys1 = (unsigned*)alloc((size_t)NTOT*4);
  unsigned* idx0  = (unsigned*)alloc((size_t)NTOT*4);
  unsigned* idx1  = (unsigned*)alloc((size_t)NTOT*4);
  unsigned* ghist = (unsigned*)alloc((size_t)256*NBLK*4);
  unsigned* dtot  = (unsigned*)alloc((size_t)256*4);
  unsigned* unsrt = (unsigned*)alloc((size_t)NTOT*4);
  float* STEP = (float*)alloc((size_t)2*(NTOT/2)*192*4);   // 50.3 MB
  float* V    = (float*)alloc((size_t)2*NTOT*16*4);        // 8 MB

  void* args[] = {
    (void*)&grad, (void*)&sharp,
    (void*)&keys0, (void*)&keys1, (void*)&idx0, (void*)&idx1,
    (void*)&ghist, (void*)&dtot, (void*)&unsrt,
    (void*)&inprojW, (void*)&inprojb, (void*)&m_inW, (void*)&m_dtW,
    (void*)&m_dtb, (void*)&m_BW, (void*)&m_CW, (void*)&STEP
  };
  hipLaunchCooperativeKernel((void*)k_sortstage, dim3(NBLK), dim3(256), args, 0, stream);

  k_scan_fused<<<dim3(CCH, 2), 256, 0, stream>>>(STEP, m_Alog, m_rope, m_D,
      mfwd, mbwd, V, out);
  k_final<<<NTOT/256, 256, 0, stream>>>(grad, sharp, gru_st, unsrt, V, m_outW,
      gWz, gbz, gWr, gbr, gWh, gbh, peer_qW, keysA, keysB, eW1, eb1, eW2, eb2, out);
}

// Round 4
// 283.049 us; speedup vs baseline: 2.3264x; 2.3264x over previous
//
#include <hip/hip_runtime.h>
#include <math.h>

#define NTOT 65536
#define LCH 128
#define WRM 128
#define CCH 512          // NTOT / LCH
#define NB 128           // sort blocks
#define EPB 512          // elements per sort block

__device__ __forceinline__ float d_softplus(float x){
  return fmaxf(x, 0.f) + log1pf(__expf(-fabsf(x)));
}
__device__ __forceinline__ float d_sigmoid(float x){
  return 1.f / (1.f + __expf(-x));
}
__device__ __forceinline__ float fast_rcp(float x){
  return __builtin_amdgcn_rcpf(x);
}
template<int CTRL>
__device__ __forceinline__ float dpp_mov(float x){
  return __int_as_float(__builtin_amdgcn_update_dpp(0, __float_as_int(x), CTRL, 0xF, 0xF, true));
}
// DPP ctrls: 0xB1 quad_perm xor1, 0x4E quad_perm xor2, 0x121 row_ror:1,
// 0x140 row_mirror, 0x141 row_half_mirror.

__device__ __forceinline__ unsigned block_incl_scan(unsigned v, unsigned* buf, int t){
  buf[t] = v; __syncthreads();
  #pragma unroll
  for (int off = 1; off < 256; off <<= 1){
    unsigned u = (t >= off) ? buf[t-off] : 0u;
    __syncthreads();
    buf[t] += u;
    __syncthreads();
  }
  unsigned r = buf[t];
  __syncthreads();
  return r;
}

// ============ k0: keys + pass-0 per-block hist (block-major) + zero next hists ====
__global__ __launch_bounds__(256) void k_keys_hist(
    const float* __restrict__ g, unsigned* __restrict__ keys0,
    unsigned* __restrict__ ghist0, unsigned* __restrict__ ghist1,
    unsigned* __restrict__ ghist2, unsigned* __restrict__ ghist3)
{
  __shared__ unsigned h[256];
  int t = threadIdx.x, blk = blockIdx.x;
  h[t] = 0u;
  __syncthreads();
  #pragma unroll
  for (int r = 0; r < 2; ++r){
    int i = blk*EPB + r*256 + t;
    unsigned key = __float_as_uint(g[i]) & 0x7fffffffu;
    keys0[i] = key;
    atomicAdd(&h[key & 255u], 1u);
  }
  __syncthreads();
  ghist0[blk*256 + t] = h[t];
  int z = blk*256 + t;        // 32768 entries per hist buffer
  ghist1[z] = 0u; ghist2[z] = 0u; ghist3[z] = 0u;
}

// ============ scatter pass P: redundant global scan + stable ballot scatter =======
// Also builds pass P+1's histogram on the fly (dest block = pos>>9).
template<int P>
__global__ __launch_bounds__(256) void k_scatter(
    const unsigned* __restrict__ keys_in, const unsigned* __restrict__ idx_in,
    unsigned* __restrict__ keys_out, unsigned* __restrict__ idx_out,
    const unsigned* __restrict__ ghist, unsigned* __restrict__ ghist_next,
    unsigned* __restrict__ unsrt)
{
  __shared__ unsigned runv[256], buf[256], shw[1024];
  int t = threadIdx.x, blk = blockIdx.x;
  int lane = t & 63, wv = t >> 6;
  // redundant global prefix: thread t owns digit t
  unsigned tot = 0u, myoff = 0u;
  for (int b = 0; b < NB; ++b){
    unsigned v = ghist[b*256 + t];      // coalesced across lanes
    if (b < blk) myoff += v;
    tot += v;
  }
  unsigned incl = block_incl_scan(tot, buf, t);
  runv[t] = (incl - tot) + myoff;
  shw[t] = 0u; shw[256+t] = 0u; shw[512+t] = 0u; shw[768+t] = 0u;
  __syncthreads();
  #pragma unroll
  for (int r = 0; r < 2; ++r){
    int i = blk*EPB + r*256 + t;
    unsigned key = keys_in[i];
    unsigned id  = (P == 0) ? (unsigned)i : idx_in[i];
    unsigned dig = (key >> (P*8)) & 255u;
    unsigned long long m = ~0ull;
    #pragma unroll
    for (int b = 0; b < 8; ++b){
      unsigned long long bb = __ballot((dig >> b) & 1u);
      m &= ((dig >> b) & 1u) ? bb : ~bb;
    }
    unsigned rank = (unsigned)__popcll(m & ((1ull << lane) - 1ull));
    unsigned cnt  = (unsigned)__popcll(m);
    if (rank == 0) shw[wv*256 + dig] = cnt;
    __syncthreads();
    unsigned pos = runv[dig] + rank;
    for (int w2 = 0; w2 < wv; ++w2) pos += shw[w2*256 + dig];
    if (P < 3){
      keys_out[pos] = key;
      idx_out[pos]  = id;
      unsigned dign = (key >> (P*8 + 8)) & 255u;
      atomicAdd(&ghist_next[(pos >> 9)*256 + dign], 1u);
    } else {
      idx_out[pos] = id;       // final sorted ids
      unsrt[id] = pos;
    }
    __syncthreads();
    runv[t] += shw[t] + shw[256+t] + shw[512+t] + shw[768+t];
    shw[t] = 0u; shw[256+t] = 0u; shw[512+t] = 0u; shw[768+t] = 0u;
    __syncthreads();
  }
}

// ============ stage X: per-sorted-position precompute, packed STEP layout =========
// Per dir, per position pair (pair=j>>1, sub=j&1), 768 B = 192 floats:
//   d-block: [d*8 + sub*4] float4 {dt, dt*xb, sz, xb}
//   s-block: [128 + s*4 + sub*2] float2 {ba, ca}
__global__ __launch_bounds__(256) void k_stagex(
    const float* __restrict__ g, const float* __restrict__ sh,
    const unsigned* __restrict__ sidx,
    const float* __restrict__ inprojW, const float* __restrict__ inprojb,
    const float* __restrict__ m_inW, const float* __restrict__ m_dtW,
    const float* __restrict__ m_dtb, const float* __restrict__ m_BW,
    const float* __restrict__ m_CW,
    float* __restrict__ STEP)
{
  __shared__ float w_in[512], w_dt[512], w_B[512], w_C[512], w_dtb[32], w_ip[16], w_ipb[8];
  int t = threadIdx.x;
  for (int k = t; k < 512; k += 256){ w_in[k]=m_inW[k]; w_dt[k]=m_dtW[k]; w_B[k]=m_BW[k]; w_C[k]=m_CW[k]; }
  if (t < 32) w_dtb[t] = m_dtb[t];
  if (t < 16) w_ip[t]  = inprojW[t];
  if (t < 8)  w_ipb[t] = inprojb[t];
  __syncthreads();
  int j = blockIdx.x*256 + t;
  unsigned i = sidx[j];
  float gj = g[i], sjv = sh[i];
  float x[8];
  #pragma unroll
  for (int mm = 0; mm < 8; ++mm) x[mm] = w_ip[mm*2]*gj + w_ip[mm*2+1]*sjv + w_ipb[mm];
  int pair = j >> 1, sub = j & 1;
  for (int dir = 0; dir < 2; ++dir){
    const float* inW = &w_in[dir*256];
    float xb[16], z[16];
    #pragma unroll
    for (int k = 0; k < 16; ++k){
      float a = 0.f, b = 0.f;
      #pragma unroll
      for (int mm = 0; mm < 8; ++mm){ a += inW[k*8+mm]*x[mm]; b += inW[(16+k)*8+mm]*x[mm]; }
      xb[k] = a; z[k] = b;
    }
    const float* dtW = &w_dt[dir*256];
    const float* BW  = &w_B[dir*256];
    const float* CW  = &w_C[dir*256];
    float* basep = STEP + (size_t)(dir*(NTOT/2) + pair)*192;
    #pragma unroll
    for (int k = 0; k < 16; ++k){
      float u = w_dtb[dir*16+k];
      #pragma unroll
      for (int mm = 0; mm < 16; ++mm) u += dtW[k*16+mm]*xb[mm];
      float dt = d_softplus(u);
      float zz = z[k];
      float sz = zz * d_sigmoid(zz);
      *(float4*)(basep + k*8 + sub*4) = make_float4(dt, dt*xb[k], sz, xb[k]);
      float bb = 0.f, cc = 0.f;
      #pragma unroll
      for (int mm = 0; mm < 16; ++mm){ bb += BW[k*16+mm]*xb[mm]; cc += CW[k*16+mm]*xb[mm]; }
      *(float2*)(basep + 128 + k*4 + sub*2) = make_float2(bb, cc);
    }
  }
}

// ============ fused scan: warm-up-from-zero chunked recurrence ============
// grid (CCH, 2). thread t: d = t>>4 (channel), s = t&15 (state).
__global__ __launch_bounds__(256) void k_scan_fused(
    const float* __restrict__ STEP, const float* __restrict__ Alog,
    const float* __restrict__ rope, const float* __restrict__ m_D,
    const float* __restrict__ mfwd, const float* __restrict__ mbwd,
    float* __restrict__ V, float* __restrict__ dout)
{
  __shared__ float lds[6144];    // 24 KB staging tile: 64 positions x 96 floats
  __shared__ float ldsV[1024];   // 4 KB V tile for coalesced writeout
  int c = blockIdx.x, dir = blockIdx.y;
  int t = threadIdx.x, d = t >> 4, s = t & 15;
  float Ah = -__expf(Alog[dir*256 + d*16 + s]) * 0.5f;
  float rp = rope[dir*256 + d*16 + s];
  float Dd = m_D[dir*16 + d];
  bool fwd = (dir == 0);
  int warm = ((fwd && c == 0) || (!fwd && c == CCH-1)) ? 0 : WRM;
  int T = (LCH + warm) >> 6;
  int warmT = warm >> 6;
  float h = (warm == 0) ? (fwd ? mfwd[t] : mbwd[t]) : 0.f;
  float* Vp = V + (size_t)dir*NTOT*16;
  const float* Sp = STEP + (size_t)dir*(NTOT/2)*192;

  float4 pf[6];
  #define TILELO(j) (fwd ? (c*LCH - warm + (j)*64) : ((c+1)*LCH + warm - ((j)+1)*64))
  {
    const float4* gp = (const float4*)(Sp + (size_t)(TILELO(0) >> 1)*192);
    #pragma unroll
    for (int k = 0; k < 6; ++k) pf[k] = gp[t + k*256];
  }
  for (int j = 0; j < T; ++j){
    if (j) __syncthreads();                       // staging + ldsV reuse barrier
    #pragma unroll
    for (int k = 0; k < 6; ++k) ((float4*)lds)[t + k*256] = pf[k];
    __syncthreads();
    if (j + 1 < T){
      const float4* gp = (const float4*)(Sp + (size_t)(TILELO(j+1) >> 1)*192);
      #pragma unroll
      for (int k = 0; k < 6; ++k) pf[k] = gp[t + k*256];
    }
    bool real = (j >= warmT);
    int lo = TILELO(j);
    for (int mb = 0; mb < 16; ++mb){
      float yv[4];
      #pragma unroll
      for (int q = 0; q < 4; ++q){
        int m = mb*4 + q;
        int lm = fwd ? m : 63 - m;
        int pr = lm >> 1, sub = lm & 1;
        float4 dd = *(const float4*)&lds[pr*192 + d*8 + sub*4];
        float2 sv = *(const float2*)&lds[pr*192 + 128 + s*4 + sub*2];
        float dt = dd.x, dxb = dd.y;
        float xh = dt * Ah;
        float Ab = (1.f + xh) * fast_rcp(1.f - xh + 1e-8f);
        // |ph| = |dt*rope| small -> 5th-order Taylor exact to fp32
        float ph = dt * rp;
        float p2 = ph * ph;
        float ccos = 1.f - p2*(0.5f - 0.041666668f*p2);
        float ssin = ph*(1.f - 0.16666667f*p2);
        float a = Ab * ccos;
        float b = -Ab * ssin;
        float hm = dpp_mov<0x121>(h);             // roll(h,1): lane s <- s-1
        h = fmaf(a, h, fmaf(b, hm, dxb * sv.x));
        if (real){
          float v = h * sv.y;
          v += dpp_mov<0xB1>(v);
          v += dpp_mov<0x4E>(v);
          v += dpp_mov<0x140>(v);
          v += dpp_mov<0x141>(v);                 // full 16-lane sum
          yv[q] = fmaf(v, dd.z, Dd * dd.w);       // y*silu(z) + D*xb
        }
      }
      if (real && s < 4){
        float val = (s == 0) ? yv[0] : ((s == 1) ? yv[1] : ((s == 2) ? yv[2] : yv[3]));
        int p = fwd ? (mb*4 + s) : (63 - (mb*4 + s));
        ldsV[p*16 + d] = val;
      }
    }
    if (real){
      __syncthreads();
      float4 vv = ((const float4*)ldsV)[t];
      ((float4*)(Vp + (size_t)lo*16))[t] = vv;    // coalesced 4 KB tile store
    }
  }
  #undef TILELO
  if ((fwd && c == CCH-1) || (!fwd && c == 0))
    dout[5*NTOT + dir*256 + t] = h;               // new_fwd / new_bwd
}

// ============ final: outW projection (gather by unsort) + GRU + PEER ============
__global__ __launch_bounds__(256) void k_final(
    const float* __restrict__ g, const float* __restrict__ sh,
    const float* __restrict__ gru_state, const unsigned* __restrict__ unsrt,
    const float* __restrict__ V, const float* __restrict__ m_outW,
    const float* __restrict__ Wz, const float* __restrict__ bz,
    const float* __restrict__ Wr, const float* __restrict__ br,
    const float* __restrict__ Wh, const float* __restrict__ bh,
    const float* __restrict__ qW, const float* __restrict__ kA, const float* __restrict__ kB,
    const float* __restrict__ eW1, const float* __restrict__ eb1,
    const float* __restrict__ eW2, const float* __restrict__ eb2,
    float* __restrict__ dout)
{
  __shared__ float sWz[88], sWr[88], sWh[88], sbz[4], sbr[4], sbh[4];
  __shared__ float sqW[704], skA[192], skB[192], sOW[256];
  __shared__ float sW1[2304], sb1[2304], sW2[2304], sb2[144];
  int t = threadIdx.x;
  for (int k = t; k < 88; k += 256){ sWz[k]=Wz[k]; sWr[k]=Wr[k]; sWh[k]=Wh[k]; }
  if (t < 4){ sbz[t]=bz[t]; sbr[t]=br[t]; sbh[t]=bh[t]; }
  sOW[t] = m_outW[t];
  for (int k = t; k < 704; k += 256) sqW[k]=qW[k];
  for (int k = t; k < 192; k += 256){ skA[k]=kA[k]; skB[k]=kB[k]; }
  for (int k = t; k < 2304; k += 256){ sW1[k]=eW1[k]; sb1[k]=eb1[k]; sW2[k]=eW2[k]; }
  for (int k = t; k < 144; k += 256) sb2[k]=eb2[k];
  __syncthreads();
  int i = blockIdx.x*256 + t;
  float gi = g[i], si = sh[i];
  unsigned j = unsrt[i];
  float xin[22];
  xin[0] = gi; xin[1] = si;
  #pragma unroll
  for (int dir = 0; dir < 2; ++dir){
    const float* vp = V + (size_t)dir*NTOT*16 + (size_t)j*16;
    float v[16];
    #pragma unroll
    for (int k = 0; k < 4; ++k){
      float4 f = ((const float4*)vp)[k];
      v[k*4] = f.x; v[k*4+1] = f.y; v[k*4+2] = f.z; v[k*4+3] = f.w;
    }
    #pragma unroll
    for (int m = 0; m < 8; ++m){
      float a = 0.f;
      #pragma unroll
      for (int k = 0; k < 16; ++k) a += sOW[dir*128 + m*16 + k]*v[k];
      xin[2 + dir*8 + m] = a;
    }
  }
  float h[4];
  #pragma unroll
  for (int k = 0; k < 4; ++k) h[k] = gru_state[i*4 + k];
  float zg[4], r[4];
  #pragma unroll
  for (int o = 0; o < 4; ++o){
    float az = sbz[o], ar = sbr[o];
    #pragma unroll
    for (int c = 0; c < 18; ++c){ az += sWz[o*22+c]*xin[c]; ar += sWr[o*22+c]*xin[c]; }
    #pragma unroll
    for (int c = 0; c < 4; ++c){ az += sWz[o*22+18+c]*h[c]; ar += sWr[o*22+18+c]*h[c]; }
    zg[o] = d_sigmoid(az);
    r[o]  = d_sigmoid(ar);
  }
  float ng[4];
  #pragma unroll
  for (int o = 0; o < 4; ++o){
    float ah = sbh[o];
    #pragma unroll
    for (int c = 0; c < 18; ++c) ah += sWh[o*22+c]*xin[c];
    #pragma unroll
    for (int c = 0; c < 4; ++c) ah += sWh[o*22+18+c]*(r[c]*h[c]);
    float ht = tanhf(ah);
    ng[o] = (1.f - zg[o])*h[o] + zg[o]*ht;
  }
  float pin[22];
  #pragma unroll
  for (int k = 0; k < 4; ++k) pin[k] = ng[k];
  #pragma unroll
  for (int m = 0; m < 16; ++m) pin[4+m] = xin[2+m];
  pin[20] = gi; pin[21] = si;
  float total = 0.f;
  #pragma unroll
  for (int hh = 0; hh < 4; ++hh){
    float qv[8];
    #pragma unroll
    for (int o = 0; o < 8; ++o){
      float a = 0.f;
      #pragma unroll
      for (int c = 0; c < 22; ++c) a += sqW[hh*176 + o*22 + c]*pin[c];
      qv[o] = a;
    }
    int ia = 0; float best = -1e30f;
    #pragma unroll
    for (int k = 0; k < 12; ++k){
      float sc = 0.f;
      #pragma unroll
      for (int m = 0; m < 4; ++m) sc += skA[hh*48 + k*4 + m]*qv[m];
      if (sc > best){ best = sc; ia = k; }
    }
    int ib = 0; best = -1e30f;
    #pragma unroll
    for (int k = 0; k < 12; ++k){
      float sc = 0.f;
      #pragma unroll
      for (int m = 0; m < 4; ++m) sc += skB[hh*48 + k*4 + m]*qv[4+m];
      if (sc > best){ best = sc; ib = k; }
    }
    int e = ia*12 + ib;
    float outv = sb2[e];
    #pragma unroll
    for (int u = 0; u < 16; ++u){
      float z1 = fmaxf(sW1[e*16+u]*gi + sb1[e*16+u], 0.f);
      outv += sW2[e*16+u]*z1;
    }
    total += outv;
  }
  total *= 0.25f;
  dout[i] = gi + 0.1f*total;
  #pragma unroll
  for (int k = 0; k < 4; ++k) dout[NTOT + i*4 + k] = ng[k];
}

extern "C" void kernel_launch(void* const* d_in, const int* in_sizes, int n_in,
                              void* d_out, int out_size, void* d_ws, size_t ws_size,
                              hipStream_t stream)
{
  const float* grad     = (const float*)d_in[0];
  const float* sharp    = (const float*)d_in[1];
  const float* gru_st   = (const float*)d_in[2];
  const float* mfwd     = (const float*)d_in[3];
  const float* mbwd     = (const float*)d_in[4];
  const float* inprojW  = (const float*)d_in[5];
  const float* inprojb  = (const float*)d_in[6];
  const float* m_inW    = (const float*)d_in[7];
  const float* m_dtW    = (const float*)d_in[8];
  const float* m_dtb    = (const float*)d_in[9];
  const float* m_BW     = (const float*)d_in[10];
  const float* m_CW     = (const float*)d_in[11];
  const float* m_Alog   = (const float*)d_in[12];
  const float* m_D      = (const float*)d_in[13];
  const float* m_rope   = (const float*)d_in[14];
  const float* m_outW   = (const float*)d_in[15];
  const float* gWz      = (const float*)d_in[16];
  const float* gbz      = (const float*)d_in[17];
  const float* gWr      = (const float*)d_in[18];
  const float* gbr      = (const float*)d_in[19];
  const float* gWh      = (const float*)d_in[20];
  const float* gbh      = (const float*)d_in[21];
  const float* peer_qW  = (const float*)d_in[22];
  const float* keysA    = (const float*)d_in[23];
  const float* keysB    = (const float*)d_in[24];
  const float* eW1      = (const float*)d_in[25];
  const float* eb1      = (const float*)d_in[26];
  const float* eW2      = (const float*)d_in[27];
  const float* eb2      = (const float*)d_in[28];
  float* out = (float*)d_out;

  char* base = (char*)d_ws;
  size_t off = 0;
  auto alloc = [&](size_t bytes)->void*{
    void* p = (void*)(base + off);
    off = (off + bytes + 255) & ~(size_t)255;
    return p;
  };
  unsigned* keys0 = (unsigned*)alloc((size_t)NTOT*4);
  unsigned* keys1 = (unsigned*)alloc((size_t)NTOT*4);
  unsigned* idx0  = (unsigned*)alloc((size_t)NTOT*4);
  unsigned* idx1  = (unsigned*)alloc((size_t)NTOT*4);
  unsigned* sidx  = (unsigned*)alloc((size_t)NTOT*4);
  unsigned* unsrt = (unsigned*)alloc((size_t)NTOT*4);
  unsigned* gh0   = (unsigned*)alloc((size_t)NB*256*4);
  unsigned* gh1   = (unsigned*)alloc((size_t)NB*256*4);
  unsigned* gh2   = (unsigned*)alloc((size_t)NB*256*4);
  unsigned* gh3   = (unsigned*)alloc((size_t)NB*256*4);
  float* STEP = (float*)alloc((size_t)2*(NTOT/2)*192*4);   // 50.3 MB
  float* V    = (float*)alloc((size_t)2*NTOT*16*4);        // 8 MB

  k_keys_hist<<<NB, 256, 0, stream>>>(grad, keys0, gh0, gh1, gh2, gh3);
  // pass 0: keys0 -> keys1, ids generated -> idx0
  k_scatter<0><<<NB, 256, 0, stream>>>(keys0, (const unsigned*)0, keys1, idx0, gh0, gh1, unsrt);
  // pass 1: keys1 -> keys0, idx0 -> idx1
  k_scatter<1><<<NB, 256, 0, stream>>>(keys1, idx0, keys0, idx1, gh1, gh2, unsrt);
  // pass 2: keys0 -> keys1, idx1 -> idx0
  k_scatter<2><<<NB, 256, 0, stream>>>(keys0, idx1, keys1, idx0, gh2, gh3, unsrt);
  // pass 3: keys1, idx0 -> sidx (+unsrt)
  k_scatter<3><<<NB, 256, 0, stream>>>(keys1, idx0, (unsigned*)0, sidx, gh3, (unsigned*)0, unsrt);

  k_stagex<<<NTOT/256, 256, 0, stream>>>(grad, sharp, sidx, inprojW, inprojb,
      m_inW, m_dtW, m_dtb, m_BW, m_CW, STEP);
  k_scan_fused<<<dim3(CCH, 2), 256, 0, stream>>>(STEP, m_Alog, m_rope, m_D,
      mfwd, mbwd, V, out);
  k_final<<<NTOT/256, 256, 0, stream>>>(grad, sharp, gru_st, unsrt, V, m_outW,
      gWz, gbz, gWr, gbr, gWh, gbh, peer_qW, keysA, keysB, eW1, eb1, eW2, eb2, out);
}